// Round 1
// baseline (249.778 us; speedup 1.0000x reference)
//
#include <hip/hip_runtime.h>
#include <cstdint>
#include <cstddef>

typedef __attribute__((ext_vector_type(8))) short bf16x8;
typedef __attribute__((ext_vector_type(4))) short bf16x4;
typedef __attribute__((ext_vector_type(4))) float f32x4;
typedef unsigned short us;

constexpr int Bsz = 4, Ssz = 2048, Dsz = 1024, Hn = 16, HDsz = 64;
constexpr int Msz = Bsz * Ssz; // 8192 rows of x
constexpr float LOG2E = 1.4426950408889634f;

// K=16 bf16 MFMA (v_mfma_f32_16x16x16_bf16). NOTE: do NOT gate amdgcn
// builtins with __has_builtin — it returns false in the HIP host pass.
#define MFMA16(a, b, c) __builtin_amdgcn_mfma_f32_16x16x16bf16_1k(a, b, c, 0, 0, 0)
#define MFMA32(a, b, c) __builtin_amdgcn_mfma_f32_16x16x32_bf16(a, b, c, 0, 0, 0)

__device__ __forceinline__ unsigned short f2bf(float f) {
  union { float f; unsigned int u; } v; v.f = f;
  unsigned int r = v.u + 0x7fffu + ((v.u >> 16) & 1u);
  return (unsigned short)(r >> 16);
}

// async 16B global -> LDS (wave-uniform LDS base + lane*16)
typedef __attribute__((address_space(1))) const unsigned int gu32;
typedef __attribute__((address_space(3))) unsigned int lu32;
__device__ __forceinline__ void async_cp16(const unsigned short* g, unsigned short* l) {
  __builtin_amdgcn_global_load_lds((gu32*)g, (lu32*)l, 16, 0, 0);
}

// ---------- fused: 4x W-transpose (z=0..3) + x fp32->bf16 (z=4) ----------
__global__ void prep_kernel(const float* __restrict__ x, unsigned short* __restrict__ xb,
                            const float* __restrict__ W0, const float* __restrict__ W1,
                            const float* __restrict__ W2, const float* __restrict__ W3,
                            unsigned short* __restrict__ T0, unsigned short* __restrict__ T1,
                            unsigned short* __restrict__ T2, unsigned short* __restrict__ T3) {
  const int z = blockIdx.z;
  if (z == 4) {  // x convert: 1024 blocks x 256 thr x 8 float4
    const int i0 = (blockIdx.y * 32 + blockIdx.x) * 2048 + threadIdx.x;
#pragma unroll
    for (int j = 0; j < 8; j++) {
      const int i = i0 + j * 256;
      const float4 v = reinterpret_cast<const float4*>(x)[i];
      ushort4 o;
      o.x = f2bf(v.x); o.y = f2bf(v.y); o.z = f2bf(v.z); o.w = f2bf(v.w);
      reinterpret_cast<ushort4*>(xb)[i] = o;
    }
    return;
  }
  __shared__ float tile[32][33];
  const float* W = (z == 0) ? W0 : (z == 1) ? W1 : (z == 2) ? W2 : W3;
  unsigned short* Wt = (z == 0) ? T0 : (z == 1) ? T1 : (z == 2) ? T2 : T3;
  int tx = threadIdx.x & 31, ty = threadIdx.x >> 5; // 32 x 8
  int bx = blockIdx.x, by = blockIdx.y;
#pragma unroll
  for (int i = 0; i < 4; i++) {
    int k = by * 32 + ty + i * 8;
    tile[ty + i * 8][tx] = W[k * Dsz + bx * 32 + tx];
  }
  __syncthreads();
#pragma unroll
  for (int i = 0; i < 4; i++) {
    int nrow = bx * 32 + ty + i * 8;
    Wt[nrow * Dsz + by * 32 + tx] = f2bf(tile[tx][ty + i * 8]);
  }
}

// ---------- 128x128-tile, BK=64, 512 threads (kept for the OUT projection) ----------
enum { EPI_QKV = 0, EPI_OUT = 1 };

template <int EPI>
__global__ __launch_bounds__(512, 4)
void gemm_bk64(const unsigned short* __restrict__ A,
               const unsigned short* __restrict__ Bt,
               unsigned short* __restrict__ Qh,
               unsigned short* __restrict__ Kh,
               unsigned short* __restrict__ Vth,
               float* __restrict__ Out,
               const float* __restrict__ bias) {
  __shared__ unsigned short As[128 * 64];
  __shared__ unsigned short Bs[128 * 64];

  const int tid = threadIdx.x;
  const int w = tid >> 6, lane = tid & 63;
  const int l15 = lane & 15, quad = lane >> 4;
  const int wr = w >> 1, wc = w & 1;
  const int bm = blockIdx.y, bn = blockIdx.x;
  const int rr = lane >> 3;                 // row within 8-row group
  const int scoff = ((lane & 7) ^ rr) * 8;  // swizzled source col (shorts)

  f32x4 acc[2][4];
#pragma unroll
  for (int i = 0; i < 2; i++)
#pragma unroll
    for (int j = 0; j < 4; j++) acc[i][j] = (f32x4){0.f, 0.f, 0.f, 0.f};

  const int rowA0 = bm * 128, rowB0 = bn * 128;

  for (int kt = 0; kt < Dsz / 64; kt++) {
#pragma unroll
    for (int i = 0; i < 2; i++) {
      const int r8 = w * 16 + i * 8;
      async_cp16(&A[(size_t)(rowA0 + r8 + rr) * Dsz + kt * 64 + scoff], &As[r8 * 64]);
      async_cp16(&Bt[(size_t)(rowB0 + r8 + rr) * Dsz + kt * 64 + scoff], &Bs[r8 * 64]);
    }
    __syncthreads();

#pragma unroll
    for (int ks = 0; ks < 2; ks++) {
      bf16x8 af[2], bfr[4];
#pragma unroll
      for (int t = 0; t < 2; t++) {
        const int ra = wr * 32 + t * 16 + l15;
        af[t] = *reinterpret_cast<const bf16x8*>(
            &As[ra * 64 + (((ks * 4 + quad) ^ (ra & 7)) * 8)]);
      }
#pragma unroll
      for (int t = 0; t < 4; t++) {
        const int rb = wc * 64 + t * 16 + l15;
        bfr[t] = *reinterpret_cast<const bf16x8*>(
            &Bs[rb * 64 + (((ks * 4 + quad) ^ (rb & 7)) * 8)]);
      }
#pragma unroll
      for (int i = 0; i < 2; i++)
#pragma unroll
        for (int j = 0; j < 4; j++)
          acc[i][j] = MFMA32(af[i], bfr[j], acc[i][j]);
    }
    __syncthreads();
  }

  if (EPI == EPI_QKV) {
    const int proj = (bn * 128) >> 10;  // block-uniform: 0=Q 1=K 2=V
#pragma unroll
    for (int i = 0; i < 2; i++) {
#pragma unroll
      for (int j = 0; j < 4; j++) {
        const int n = bn * 128 + wc * 64 + j * 16 + l15;
        const int nn = n & 1023, h = nn >> 6, hd = nn & 63;
        const int m0 = bm * 128 + wr * 32 + i * 16 + quad * 4;
        const int b = m0 >> 11, s0 = m0 & (Ssz - 1);
        if (proj == 0) {
#pragma unroll
          for (int r = 0; r < 4; r++)
            Qh[((size_t)(b * Hn + h) * Ssz + s0 + r) * HDsz + hd] =
                f2bf(acc[i][j][r] * (0.125f * LOG2E));
        } else if (proj == 1) {
#pragma unroll
          for (int r = 0; r < 4; r++)
            Kh[((size_t)(b * Hn + h) * Ssz + s0 + r) * HDsz + hd] = f2bf(acc[i][j][r]);
        } else {
          ushort4 o;
          o.x = f2bf(acc[i][j][0]); o.y = f2bf(acc[i][j][1]);
          o.z = f2bf(acc[i][j][2]); o.w = f2bf(acc[i][j][3]);
          *reinterpret_cast<ushort4*>(
              &Vth[((size_t)(b * Hn + h) * HDsz + hd) * Ssz + s0]) = o;
        }
      }
    }
  } else {
#pragma unroll
    for (int i = 0; i < 2; i++) {
#pragma unroll
      for (int j = 0; j < 4; j++) {
        const int n = bn * 128 + wc * 64 + j * 16 + l15;
        const int m0 = bm * 128 + wr * 32 + i * 16 + quad * 4;
#pragma unroll
        for (int r = 0; r < 4; r++)
          Out[(size_t)(m0 + r) * Dsz + n] = acc[i][j][r] + bias[n];
      }
    }
  }
}

// ---------- 256x256-tile 8-phase QKV GEMM (T2+T3+T4+T5 per m201 template) ----------
// 512 thr = 8 waves (2M x 4N), per-wave C = 128x64 with INTERLEAVED m-reps:
// m-rep i covers rows 32*i + wr*16, so each phase's A reads form a contiguous
// 64-row stripe that dies at end-of-phase. B (all 4 quarters) dies in phase 1.
// Staging (2 x global_load_lds / phase) always lands on a region whose last
// reader finished >=1 barrier earlier:
//   ph1: next-tile stripe3 + B-q3  -> OTHER buffer (read there last phase-4/1)
//   ph2..4: tile(t+2) stripes 0..2 + B-q0..2 -> CURRENT buffer (just read)
// vmcnt(6) only at phase 4: drains exactly through tile(t+1)'s last pair,
// leaving tile(t+2)'s 6 stages in flight. vmcnt(0) at t=14, none at t=15.
#define BARRIER() do { asm volatile("" ::: "memory"); __builtin_amdgcn_s_barrier(); asm volatile("" ::: "memory"); } while (0)
#define LGKM0() asm volatile("s_waitcnt lgkmcnt(0)" ::: "memory")
#define VMW6()  asm volatile("s_waitcnt vmcnt(6)" ::: "memory")
#define VMW0()  asm volatile("s_waitcnt vmcnt(0)" ::: "memory")
#define CFENCE() asm volatile("" ::: "memory")

#define PHASE_TAIL(P, AF)                                                   \
  BARRIER(); LGKM0();                                                       \
  __builtin_amdgcn_s_setprio(1);                                            \
  _Pragma("unroll")                                                         \
  for (int ks = 0; ks < 2; ks++)                                            \
    _Pragma("unroll")                                                       \
    for (int im = 0; im < 2; im++)                                          \
      _Pragma("unroll")                                                     \
      for (int n = 0; n < 4; n++)                                           \
        acc[2 * (P) + im][n] = MFMA32(AF[im][ks], bfr[n][ks], acc[2 * (P) + im][n]); \
  __builtin_amdgcn_s_setprio(0);

#define KTILE(Ac, Bc, Ao, Bo, U) do {                                       \
  const int u_ = (U);                                                       \
  { /* phase 1: read all B + A stripe0; stage (u+1) stripe3/q3 -> other */  \
    bf16x8 af[2][2];                                                        \
    rdB(Bc);                                                                \
    rdA(Ac, 0, af);                                                         \
    if (u_ + 1 < 16) { stA(Ao, 3, u_ + 1); stB(Bo, 3, u_ + 1); }            \
    PHASE_TAIL(0, af); BARRIER();                                           \
  }                                                                         \
  { /* phase 2 */                                                           \
    bf16x8 af[2][2];                                                        \
    rdA(Ac, 1, af);                                                         \
    if (u_ + 2 < 16) { stA(Ac, 0, u_ + 2); stB(Bc, 0, u_ + 2); }            \
    PHASE_TAIL(1, af); BARRIER();                                           \
  }                                                                         \
  { /* phase 3 */                                                           \
    bf16x8 af[2][2];                                                        \
    rdA(Ac, 2, af);                                                         \
    if (u_ + 2 < 16) { stA(Ac, 1, u_ + 2); stB(Bc, 1, u_ + 2); }            \
    PHASE_TAIL(2, af); BARRIER();                                           \
  }                                                                         \
  { /* phase 4: counted vmcnt, never 0 in steady state */                   \
    bf16x8 af[2][2];                                                        \
    rdA(Ac, 3, af);                                                         \
    if (u_ + 2 < 16) { stA(Ac, 2, u_ + 2); stB(Bc, 2, u_ + 2); }            \
    PHASE_TAIL(3, af);                                                      \
    if (u_ < 14) { VMW6(); } else if (u_ == 14) { VMW0(); }                 \
    BARRIER();                                                              \
  }                                                                         \
} while (0)

__global__ __launch_bounds__(512, 2)
void gemm256_qkv(const us* __restrict__ A, const us* __restrict__ Bt,
                 us* __restrict__ Qh, us* __restrict__ Kh, us* __restrict__ Vth) {
  __shared__ us As0[256 * 64];
  __shared__ us Bs0[256 * 64];
  __shared__ us As1[256 * 64];
  __shared__ us Bs1[256 * 64];

  const int tid = threadIdx.x;
  const int w = tid >> 6, lane = tid & 63;
  const int l15 = lane & 15, quad = lane >> 4;
  const int wr = w >> 2, wc = w & 3;       // 2 x 4 wave grid
  const int rr = lane >> 3;
  const int sc16 = ((lane & 7) ^ rr) * 8;  // pre-swizzled source col (shorts)

  // bijective XCD swizzle: 384 blocks, 48 consecutive tiles per XCD (col-major)
  const int orig = blockIdx.y * 12 + blockIdx.x;
  const int swz = (orig & 7) * 48 + (orig >> 3);
  const int bn = swz / 32, bm = swz % 32;

  const size_t rowA0 = (size_t)bm * 256, rowB0 = (size_t)bn * 256;

  f32x4 acc[8][4];
#pragma unroll
  for (int i = 0; i < 8; i++)
#pragma unroll
    for (int j = 0; j < 4; j++) acc[i][j] = (f32x4){0.f, 0.f, 0.f, 0.f};

  bf16x8 bfr[4][2];  // B frags: read in phase 1, live for the whole K-tile

  // one call = workgroup stages a 64-row x 64-col (8 KB) chunk
  auto stA = [&](us* L, int stripe, int t) {
    async_cp16(&A[(rowA0 + stripe * 64 + 8 * w + rr) * (size_t)Dsz + t * 64 + sc16],
               &L[(stripe * 64 + 8 * w) * 64]);
  };
  auto stB = [&](us* L, int stripe, int t) {
    async_cp16(&Bt[(rowB0 + stripe * 64 + 8 * w + rr) * (size_t)Dsz + t * 64 + sc16],
               &L[(stripe * 64 + 8 * w) * 64]);
  };
  auto rdA = [&](const us* L, int P, bf16x8 (&af)[2][2]) {
#pragma unroll
    for (int im = 0; im < 2; im++)
#pragma unroll
      for (int ks = 0; ks < 2; ks++) {
        const int ra = P * 64 + im * 32 + wr * 16 + l15;
        af[im][ks] = *reinterpret_cast<const bf16x8*>(
            &L[ra * 64 + (((ks * 4 + quad) ^ (ra & 7)) * 8)]);
      }
  };
  auto rdB = [&](const us* L) {
#pragma unroll
    for (int n = 0; n < 4; n++)
#pragma unroll
      for (int ks = 0; ks < 2; ks++) {
        const int rb = wc * 64 + n * 16 + l15;
        bfr[n][ks] = *reinterpret_cast<const bf16x8*>(
            &L[rb * 64 + (((ks * 4 + quad) ^ (rb & 7)) * 8)]);
      }
  };

  // prologue: tile0 fully (8 calls, oldest), then tile1 stripes 0..2 (6 calls)
#pragma unroll
  for (int s = 0; s < 4; s++) { stA(As0, s, 0); stB(Bs0, s, 0); }
  CFENCE();  // pin issue order: tile0 group strictly older than tile1 group
#pragma unroll
  for (int s = 0; s < 3; s++) { stA(As1, s, 1); stB(Bs1, s, 1); }
  VMW6();  // oldest 8 (= all of tile0) landed; tile1's 6 still in flight
  BARRIER();

#pragma unroll 1
  for (int t2 = 0; t2 < 16; t2 += 2) {
    KTILE(As0, Bs0, As1, Bs1, t2);
    KTILE(As1, Bs1, As0, Bs0, t2 + 1);
  }

  // epilogue: C row = bm*256 + 32*i + wr*16 + quad*4 + r ; col = bn*256 + wc*64 + 16*j + l15
  const int proj = bn >> 2;  // block-uniform: 0=Q 1=K 2=V (256 | 1024)
#pragma unroll
  for (int i = 0; i < 8; i++) {
#pragma unroll
    for (int j = 0; j < 4; j++) {
      const int n = bn * 256 + wc * 64 + j * 16 + l15;
      const int nn = n & 1023, h = nn >> 6, hd = nn & 63;
      const int m0 = bm * 256 + i * 32 + wr * 16 + quad * 4;
      const int b = m0 >> 11, s0 = m0 & (Ssz - 1);
      if (proj == 0) {
#pragma unroll
        for (int r = 0; r < 4; r++)
          Qh[((size_t)(b * Hn + h) * Ssz + s0 + r) * HDsz + hd] =
              f2bf(acc[i][j][r] * (0.125f * LOG2E));
      } else if (proj == 1) {
#pragma unroll
        for (int r = 0; r < 4; r++)
          Kh[((size_t)(b * Hn + h) * Ssz + s0 + r) * HDsz + hd] = f2bf(acc[i][j][r]);
      } else {
        ushort4 o;
        o.x = f2bf(acc[i][j][0]); o.y = f2bf(acc[i][j][1]);
        o.z = f2bf(acc[i][j][2]); o.w = f2bf(acc[i][j][3]);
        *reinterpret_cast<ushort4*>(
            &Vth[((size_t)(b * Hn + h) * HDsz + hd) * Ssz + s0]) = o;
      }
    }
  }
}

// ---------- flash attention: 128-row tiles, balanced t-perm, S^T + reg P ----------
__global__ __launch_bounds__(256, 4)
void flash_kernel(const unsigned short* __restrict__ Q,
                  const unsigned short* __restrict__ Kg,
                  const unsigned short* __restrict__ Vt,
                  unsigned short* __restrict__ AO) {
  __shared__ unsigned short Ks[64 * 64];
  __shared__ unsigned short Vs[64 * 64];

  const int tid = threadIdx.x;
  const int w = tid >> 6, lane = tid & 63;
  const int l15 = lane & 15, quad = lane >> 4;
  const int rr = lane >> 3;

  const int linear = blockIdx.y * 16 + blockIdx.x;
  const int bh = (linear & 7) * 8 + ((linear >> 3) & 7);
  const int g = linear >> 6, gk = g >> 2, ga = g & 3;
  const int t = (gk == 0) ? 15 - ga : (gk == 1) ? 8 + ga : (gk == 2) ? 7 - ga : ga;

  const unsigned short* Qb = Q + (size_t)bh * Ssz * HDsz;
  const unsigned short* Kb = Kg + (size_t)bh * Ssz * HDsz;
  const unsigned short* Vb = Vt + (size_t)bh * HDsz * Ssz;
  const int b = bh / Hn, h = bh % Hn;

  const int hl = (l15 & 7) ^ ((l15 >> 3) << 2);

  const int q0 = t * 128;
  const int rowStart = q0 + w * 32;

  bf16x8 qf[2][2];
#pragma unroll
  for (int tm = 0; tm < 2; tm++)
#pragma unroll
    for (int ks = 0; ks < 2; ks++)
      qf[tm][ks] = *reinterpret_cast<const bf16x8*>(
          &Qb[(size_t)(rowStart + tm * 16 + l15) * HDsz + ks * 32 + quad * 8]);

  f32x4 oacc[2][4];
  float lpart[2] = {0.f, 0.f};
#pragma unroll
  for (int tm = 0; tm < 2; tm++)
#pragma unroll
    for (int tn = 0; tn < 4; tn++) oacc[tm][tn] = (f32x4){0.f, 0.f, 0.f, 0.f};

  const int nkb = 2 * t + 2;
  for (int kb = 0; kb < nkb; kb++) {
    const int kv0 = kb * 64;
#pragma unroll
    for (int i = 0; i < 2; i++) {
      const int r8 = w * 16 + i * 8;
      const int sc = (((lane & 7) ^ rr ^ (i << 2))) * 8;
      async_cp16(&Kb[(size_t)(kv0 + r8 + rr) * HDsz + sc], &Ks[r8 * 64]);
      async_cp16(&Vb[(size_t)(r8 + rr) * Ssz + kv0 + sc], &Vs[r8 * 64]);
    }
    __syncthreads();

    const bool skip = (kv0 >= rowStart + 32);
    if (!skip) {
      f32x4 sc[4][2];
#pragma unroll
      for (int tn = 0; tn < 4; tn++)
#pragma unroll
        for (int tm = 0; tm < 2; tm++) sc[tn][tm] = (f32x4){0.f, 0.f, 0.f, 0.f};
#pragma unroll
      for (int ks = 0; ks < 2; ks++) {
#pragma unroll
        for (int tn = 0; tn < 4; tn++) {
          const int rk = tn * 16 + l15;
          bf16x8 kf = *reinterpret_cast<const bf16x8*>(
              &Ks[rk * 64 + (((ks * 4 + quad) ^ hl) * 8)]);
#pragma unroll
          for (int tm = 0; tm < 2; tm++)
            sc[tn][tm] = MFMA32(kf, qf[tm][ks], sc[tn][tm]);
        }
      }

      const bool needMask = (kv0 + 63 > rowStart);
      if (needMask) {
#pragma unroll
        for (int tn = 0; tn < 4; tn++)
#pragma unroll
          for (int tm = 0; tm < 2; tm++) {
            const int qrow = rowStart + tm * 16 + l15;
#pragma unroll
            for (int r = 0; r < 4; r++)
              if (kv0 + tn * 16 + quad * 4 + r > qrow) sc[tn][tm][r] = -1e30f;
          }
      }

      unsigned int pk[4][2][2];
#pragma unroll
      for (int tn = 0; tn < 4; tn++)
#pragma unroll
        for (int tm = 0; tm < 2; tm++) {
          union { float f; unsigned int u; } e0, e1, e2, e3;
          e0.f = __builtin_amdgcn_exp2f(sc[tn][tm][0]);
          e1.f = __builtin_amdgcn_exp2f(sc[tn][tm][1]);
          e2.f = __builtin_amdgcn_exp2f(sc[tn][tm][2]);
          e3.f = __builtin_amdgcn_exp2f(sc[tn][tm][3]);
          lpart[tm] += (e0.f + e1.f) + (e2.f + e3.f);
          pk[tn][tm][0] = __builtin_amdgcn_perm(e1.u, e0.u, 0x07060302u);
          pk[tn][tm][1] = __builtin_amdgcn_perm(e3.u, e2.u, 0x07060302u);
        }

#pragma unroll
      for (int tn = 0; tn < 4; tn++) {
        bf16x4 pa[2];
#pragma unroll
        for (int tm = 0; tm < 2; tm++) {
          union { unsigned int u[2]; bf16x4 v; } cv;
          cv.u[0] = pk[tn][tm][0]; cv.u[1] = pk[tn][tm][1];
          pa[tm] = cv.v;
        }
#pragma unroll
        for (int to = 0; to < 4; to++) {
          const int rv = to * 16 + l15;
          const int chunk = tn * 2 + (quad >> 1);
          bf16x4 vf = *reinterpret_cast<const bf16x4*>(
              (const char*)Vs + rv * 128 + ((chunk ^ hl) * 16) + (quad & 1) * 8);
#pragma unroll
          for (int tm = 0; tm < 2; tm++)
            oacc[tm][to] = MFMA16(pa[tm], vf, oacc[tm][to]);
        }
      }
    }
    __syncthreads();
  }

#pragma unroll
  for (int tm = 0; tm < 2; tm++) {
    float lf = lpart[tm];
    lf += __shfl_xor(lf, 16);
    lf += __shfl_xor(lf, 32);
    float linv[4];
#pragma unroll
    for (int r = 0; r < 4; r++) {
      union { float f; int i; } cv;
      cv.f = lf;
      cv.i = __builtin_amdgcn_ds_bpermute((quad * 4 + r) * 4, cv.i);
      linv[r] = 1.f / cv.f;
    }
#pragma unroll
    for (int r = 0; r < 4; r++) {
      const int s = rowStart + tm * 16 + quad * 4 + r;
      const size_t m = (size_t)b * Ssz + s;
#pragma unroll
      for (int tn = 0; tn < 4; tn++) {
        const int n = h * HDsz + tn * 16 + l15;
        AO[m * Dsz + n] = f2bf(oacc[tm][tn][r] * linv[r]);
      }
    }
  }
}

extern "C" void kernel_launch(void* const* d_in, const int* in_sizes, int n_in,
                              void* d_out, int out_size, void* d_ws, size_t ws_size,
                              hipStream_t stream) {
  const float* x  = (const float*)d_in[0];
  const float* Wq = (const float*)d_in[1];
  const float* Wk = (const float*)d_in[2];
  const float* Wv = (const float*)d_in[3];
  const float* Wo = (const float*)d_in[4];
  const float* bo = (const float*)d_in[5];
  float* out = (float*)d_out;

  unsigned short* xb  = (unsigned short*)d_ws;
  unsigned short* Wqt = xb + (size_t)Msz * Dsz;   // Wqt/Wkt/Wvt consecutive = concat [3072][1024]
  unsigned short* Wkt = Wqt + (size_t)Dsz * Dsz;
  unsigned short* Wvt = Wkt + (size_t)Dsz * Dsz;
  unsigned short* Wot = Wvt + (size_t)Dsz * Dsz;
  unsigned short* Qh  = Wot + (size_t)Dsz * Dsz;
  unsigned short* Kh  = Qh + (size_t)Msz * Dsz;
  unsigned short* Vth = Kh + (size_t)Msz * Dsz;
  unsigned short* AO  = Vth + (size_t)Msz * Dsz;

  prep_kernel<<<dim3(32, 32, 5), 256, 0, stream>>>(
      x, xb, Wq, Wk, Wv, Wo, Wqt, Wkt, Wvt, Wot);

  // fused QKV projection: 256x256 tiles, 8-phase counted-vmcnt schedule
  gemm256_qkv<<<dim3(12, 32), 512, 0, stream>>>(xb, Wqt, Qh, Kh, Vth);

  flash_kernel<<<dim3(16, Bsz * Hn), 256, 0, stream>>>(Qh, Kh, Vth, AO);

  gemm_bk64<EPI_OUT><<<dim3(Dsz / 128, Msz / 128), 512, 0, stream>>>(
      AO, Wot, nullptr, nullptr, nullptr, out, bo);
}

// Round 2
// 237.903 us; speedup vs baseline: 1.0499x; 1.0499x over previous
//
#include <hip/hip_runtime.h>
#include <cstdint>
#include <cstddef>

typedef __attribute__((ext_vector_type(8))) short bf16x8;
typedef __attribute__((ext_vector_type(4))) short bf16x4;
typedef __attribute__((ext_vector_type(4))) float f32x4;
typedef unsigned short us;

constexpr int Bsz = 4, Ssz = 2048, Dsz = 1024, Hn = 16, HDsz = 64;
constexpr int Msz = Bsz * Ssz; // 8192 rows of x
constexpr float LOG2E = 1.4426950408889634f;

// K=16 bf16 MFMA (v_mfma_f32_16x16x16_bf16). NOTE: do NOT gate amdgcn
// builtins with __has_builtin — it returns false in the HIP host pass.
#define MFMA16(a, b, c) __builtin_amdgcn_mfma_f32_16x16x16bf16_1k(a, b, c, 0, 0, 0)
#define MFMA32(a, b, c) __builtin_amdgcn_mfma_f32_16x16x32_bf16(a, b, c, 0, 0, 0)

__device__ __forceinline__ unsigned short f2bf(float f) {
  union { float f; unsigned int u; } v; v.f = f;
  unsigned int r = v.u + 0x7fffu + ((v.u >> 16) & 1u);
  return (unsigned short)(r >> 16);
}

// async 16B global -> LDS (wave-uniform LDS base + lane*16)
typedef __attribute__((address_space(1))) const unsigned int gu32;
typedef __attribute__((address_space(3))) unsigned int lu32;
__device__ __forceinline__ void async_cp16(const unsigned short* g, unsigned short* l) {
  __builtin_amdgcn_global_load_lds((gu32*)g, (lu32*)l, 16, 0, 0);
}

// ---------- fused: 4x W-transpose (z=0..3) + x fp32->bf16 (z=4) ----------
__global__ void prep_kernel(const float* __restrict__ x, unsigned short* __restrict__ xb,
                            const float* __restrict__ W0, const float* __restrict__ W1,
                            const float* __restrict__ W2, const float* __restrict__ W3,
                            unsigned short* __restrict__ T0, unsigned short* __restrict__ T1,
                            unsigned short* __restrict__ T2, unsigned short* __restrict__ T3) {
  const int z = blockIdx.z;
  if (z == 4) {  // x convert: 1024 blocks x 256 thr x 8 float4
    const int i0 = (blockIdx.y * 32 + blockIdx.x) * 2048 + threadIdx.x;
#pragma unroll
    for (int j = 0; j < 8; j++) {
      const int i = i0 + j * 256;
      const float4 v = reinterpret_cast<const float4*>(x)[i];
      ushort4 o;
      o.x = f2bf(v.x); o.y = f2bf(v.y); o.z = f2bf(v.z); o.w = f2bf(v.w);
      reinterpret_cast<ushort4*>(xb)[i] = o;
    }
    return;
  }
  __shared__ float tile[32][33];
  const float* W = (z == 0) ? W0 : (z == 1) ? W1 : (z == 2) ? W2 : W3;
  unsigned short* Wt = (z == 0) ? T0 : (z == 1) ? T1 : (z == 2) ? T2 : T3;
  int tx = threadIdx.x & 31, ty = threadIdx.x >> 5; // 32 x 8
  int bx = blockIdx.x, by = blockIdx.y;
#pragma unroll
  for (int i = 0; i < 4; i++) {
    int k = by * 32 + ty + i * 8;
    tile[ty + i * 8][tx] = W[k * Dsz + bx * 32 + tx];
  }
  __syncthreads();
#pragma unroll
  for (int i = 0; i < 4; i++) {
    int nrow = bx * 32 + ty + i * 8;
    Wt[nrow * Dsz + by * 32 + tx] = f2bf(tile[tx][ty + i * 8]);
  }
}

// ---------- 128x128-tile, BK=64, 512 threads (kept for the OUT projection) ----------
enum { EPI_QKV = 0, EPI_OUT = 1 };

template <int EPI>
__global__ __launch_bounds__(512, 4)
void gemm_bk64(const unsigned short* __restrict__ A,
               const unsigned short* __restrict__ Bt,
               unsigned short* __restrict__ Qh,
               unsigned short* __restrict__ Kh,
               unsigned short* __restrict__ Vth,
               float* __restrict__ Out,
               const float* __restrict__ bias) {
  __shared__ unsigned short As[128 * 64];
  __shared__ unsigned short Bs[128 * 64];

  const int tid = threadIdx.x;
  const int w = tid >> 6, lane = tid & 63;
  const int l15 = lane & 15, quad = lane >> 4;
  const int wr = w >> 1, wc = w & 1;
  const int bm = blockIdx.y, bn = blockIdx.x;
  const int rr = lane >> 3;                 // row within 8-row group
  const int scoff = ((lane & 7) ^ rr) * 8;  // swizzled source col (shorts)

  f32x4 acc[2][4];
#pragma unroll
  for (int i = 0; i < 2; i++)
#pragma unroll
    for (int j = 0; j < 4; j++) acc[i][j] = (f32x4){0.f, 0.f, 0.f, 0.f};

  const int rowA0 = bm * 128, rowB0 = bn * 128;

  for (int kt = 0; kt < Dsz / 64; kt++) {
#pragma unroll
    for (int i = 0; i < 2; i++) {
      const int r8 = w * 16 + i * 8;
      async_cp16(&A[(size_t)(rowA0 + r8 + rr) * Dsz + kt * 64 + scoff], &As[r8 * 64]);
      async_cp16(&Bt[(size_t)(rowB0 + r8 + rr) * Dsz + kt * 64 + scoff], &Bs[r8 * 64]);
    }
    __syncthreads();

#pragma unroll
    for (int ks = 0; ks < 2; ks++) {
      bf16x8 af[2], bfr[4];
#pragma unroll
      for (int t = 0; t < 2; t++) {
        const int ra = wr * 32 + t * 16 + l15;
        af[t] = *reinterpret_cast<const bf16x8*>(
            &As[ra * 64 + (((ks * 4 + quad) ^ (ra & 7)) * 8)]);
      }
#pragma unroll
      for (int t = 0; t < 4; t++) {
        const int rb = wc * 64 + t * 16 + l15;
        bfr[t] = *reinterpret_cast<const bf16x8*>(
            &Bs[rb * 64 + (((ks * 4 + quad) ^ (rb & 7)) * 8)]);
      }
#pragma unroll
      for (int i = 0; i < 2; i++)
#pragma unroll
        for (int j = 0; j < 4; j++)
          acc[i][j] = MFMA32(af[i], bfr[j], acc[i][j]);
    }
    __syncthreads();
  }

  if (EPI == EPI_QKV) {
    const int proj = (bn * 128) >> 10;  // block-uniform: 0=Q 1=K 2=V
#pragma unroll
    for (int i = 0; i < 2; i++) {
#pragma unroll
      for (int j = 0; j < 4; j++) {
        const int n = bn * 128 + wc * 64 + j * 16 + l15;
        const int nn = n & 1023, h = nn >> 6, hd = nn & 63;
        const int m0 = bm * 128 + wr * 32 + i * 16 + quad * 4;
        const int b = m0 >> 11, s0 = m0 & (Ssz - 1);
        if (proj == 0) {
#pragma unroll
          for (int r = 0; r < 4; r++)
            Qh[((size_t)(b * Hn + h) * Ssz + s0 + r) * HDsz + hd] =
                f2bf(acc[i][j][r] * (0.125f * LOG2E));
        } else if (proj == 1) {
#pragma unroll
          for (int r = 0; r < 4; r++)
            Kh[((size_t)(b * Hn + h) * Ssz + s0 + r) * HDsz + hd] = f2bf(acc[i][j][r]);
        } else {
          ushort4 o;
          o.x = f2bf(acc[i][j][0]); o.y = f2bf(acc[i][j][1]);
          o.z = f2bf(acc[i][j][2]); o.w = f2bf(acc[i][j][3]);
          *reinterpret_cast<ushort4*>(
              &Vth[((size_t)(b * Hn + h) * HDsz + hd) * Ssz + s0]) = o;
        }
      }
    }
  } else {
#pragma unroll
    for (int i = 0; i < 2; i++) {
#pragma unroll
      for (int j = 0; j < 4; j++) {
        const int n = bn * 128 + wc * 64 + j * 16 + l15;
        const int m0 = bm * 128 + wr * 32 + i * 16 + quad * 4;
#pragma unroll
        for (int r = 0; r < 4; r++)
          Out[(size_t)(m0 + r) * Dsz + n] = acc[i][j][r] + bias[n];
      }
    }
  }
}

// ---------- 256x192-tile 8-phase QKV GEMM (T2+T3+T4+T5), 512 blocks = 2 full rounds ----------
// 512 thr = 8 waves (2M x 4N), per-wave C = 128x48. A m-reps interleaved
// (row = 32*i + wr*16) so phase P reads the contiguous A stripe [64P,64P+64).
// B (3 frags) read once per K-tile in phase 1, live in regs all 4 phases.
// 7 stages per K-tile (A: 4 x 64-row, B: 3 x 64-row). Steady-state issue:
//   ph1: {u+1 A3, u+1 B2} -> other buf   (completes tile u+1)
//   ph2: {u+2 A0, u+2 B0} -> cur buf     (stripe 0 was read in ph1)
//   ph3: {u+2 A1, u+2 B1} -> cur
//   ph4: {u+2 A2}         -> cur
// vmcnt(5) at ph4 drains exactly tile u+1's 7 loads (issue->wait >= 3 phases),
// leaves tile u+2's 5 in flight. vmcnt(0) at u=14; u=15 reads only.
#define BARRIER() do { asm volatile("" ::: "memory"); __builtin_amdgcn_s_barrier(); asm volatile("" ::: "memory"); } while (0)
#define LGKM0() do { asm volatile("s_waitcnt lgkmcnt(0)" ::: "memory"); __builtin_amdgcn_sched_barrier(0); } while (0)
#define VMW5()  asm volatile("s_waitcnt vmcnt(5)" ::: "memory")
#define VMW0()  asm volatile("s_waitcnt vmcnt(0)" ::: "memory")
#define CFENCE() asm volatile("" ::: "memory")

#define PHASE_TAIL(P, AF)                                                   \
  BARRIER(); LGKM0();                                                       \
  __builtin_amdgcn_s_setprio(1);                                            \
  _Pragma("unroll")                                                         \
  for (int ks = 0; ks < 2; ks++)                                            \
    _Pragma("unroll")                                                       \
    for (int im = 0; im < 2; im++)                                          \
      _Pragma("unroll")                                                     \
      for (int n = 0; n < 3; n++)                                           \
        acc[2 * (P) + im][n] = MFMA32(AF[im][ks], bfr[n][ks], acc[2 * (P) + im][n]); \
  __builtin_amdgcn_s_setprio(0);

#define KTILE(Ac, Bc, Ao, Bo, U) do {                                       \
  const int u_ = (U);                                                       \
  { /* phase 1: read all B + A stripe0; complete tile u+1 in other buf */   \
    bf16x8 af[2][2];                                                        \
    rdB(Bc);                                                                \
    rdA(Ac, 0, af);                                                         \
    if (u_ + 1 < 16) { stA(Ao, 3, u_ + 1); stB(Bo, 2, u_ + 1); }            \
    PHASE_TAIL(0, af); BARRIER();                                           \
  }                                                                         \
  { /* phase 2 */                                                           \
    bf16x8 af[2][2];                                                        \
    rdA(Ac, 1, af);                                                         \
    if (u_ + 2 < 16) { stA(Ac, 0, u_ + 2); stB(Bc, 0, u_ + 2); }            \
    PHASE_TAIL(1, af); BARRIER();                                           \
  }                                                                         \
  { /* phase 3 */                                                           \
    bf16x8 af[2][2];                                                        \
    rdA(Ac, 2, af);                                                         \
    if (u_ + 2 < 16) { stA(Ac, 1, u_ + 2); stB(Bc, 1, u_ + 2); }            \
    PHASE_TAIL(2, af); BARRIER();                                           \
  }                                                                         \
  { /* phase 4: counted vmcnt, never 0 in steady state */                   \
    bf16x8 af[2][2];                                                        \
    rdA(Ac, 3, af);                                                         \
    if (u_ + 2 < 16) { stA(Ac, 2, u_ + 2); }                                \
    PHASE_TAIL(3, af);                                                      \
    if (u_ < 14) { VMW5(); } else if (u_ == 14) { VMW0(); }                 \
    BARRIER();                                                              \
  }                                                                         \
} while (0)

__global__ __launch_bounds__(512, 2)
void gemm192_qkv(const us* __restrict__ A, const us* __restrict__ Bt,
                 us* __restrict__ Qh, us* __restrict__ Kh, us* __restrict__ Vth) {
  __shared__ us As0[256 * 64];
  __shared__ us Bs0[192 * 64];
  __shared__ us As1[256 * 64];
  __shared__ us Bs1[192 * 64];

  const int tid = threadIdx.x;
  const int w = tid >> 6, lane = tid & 63;
  const int l15 = lane & 15, quad = lane >> 4;
  const int wr = w >> 2, wc = w & 3;       // 2 x 4 wave grid
  const int rr = lane >> 3;
  const int sc16 = ((lane & 7) ^ rr) * 8;  // pre-swizzled source col (shorts)

  // bijective bm-chunked XCD swizzle: 512 blocks = 8 XCD x (4 bm x 16 bn).
  // Per-XCD A working set = 4 x 0.5MB = 2MB (L2-resident); B via L3.
  const int orig = blockIdx.y * 16 + blockIdx.x;
  const int xcd = orig & 7, idx = orig >> 3;   // idx in [0,64)
  const int bm = xcd * 4 + (idx & 3);          // [0,32)
  const int bn = idx >> 2;                     // [0,16)

  const size_t rowA0 = (size_t)bm * 256, rowB0 = (size_t)bn * 192;

  f32x4 acc[8][3];
#pragma unroll
  for (int i = 0; i < 8; i++)
#pragma unroll
    for (int j = 0; j < 3; j++) acc[i][j] = (f32x4){0.f, 0.f, 0.f, 0.f};

  bf16x8 bfr[3][2];  // B frags: read in phase 1, live for the whole K-tile

  // one call = workgroup stages a 64-row x 64-col (8 KB) chunk
  auto stA = [&](us* L, int stripe, int t) {
    async_cp16(&A[(rowA0 + stripe * 64 + 8 * w + rr) * (size_t)Dsz + t * 64 + sc16],
               &L[(stripe * 64 + 8 * w) * 64]);
  };
  auto stB = [&](us* L, int stripe, int t) {
    async_cp16(&Bt[(rowB0 + stripe * 64 + 8 * w + rr) * (size_t)Dsz + t * 64 + sc16],
               &L[(stripe * 64 + 8 * w) * 64]);
  };
  auto rdA = [&](const us* L, int P, bf16x8 (&af)[2][2]) {
#pragma unroll
    for (int im = 0; im < 2; im++)
#pragma unroll
      for (int ks = 0; ks < 2; ks++) {
        const int ra = P * 64 + im * 32 + wr * 16 + l15;
        af[im][ks] = *reinterpret_cast<const bf16x8*>(
            &L[ra * 64 + (((ks * 4 + quad) ^ (ra & 7)) * 8)]);
      }
  };
  auto rdB = [&](const us* L) {
#pragma unroll
    for (int n = 0; n < 3; n++)
#pragma unroll
      for (int ks = 0; ks < 2; ks++) {
        const int rb = wc * 48 + n * 16 + l15;
        bfr[n][ks] = *reinterpret_cast<const bf16x8*>(
            &L[rb * 64 + (((ks * 4 + quad) ^ (rb & 7)) * 8)]);
      }
  };

  // prologue: tile0 fully (7 calls, oldest), then tile1's {A0,B0,A1,B1,A2}
#pragma unroll
  for (int s = 0; s < 4; s++) stA(As0, s, 0);
#pragma unroll
  for (int s = 0; s < 3; s++) stB(Bs0, s, 0);
  CFENCE();  // pin issue order: tile0 group strictly older than tile1 group
  stA(As1, 0, 1); stB(Bs1, 0, 1); stA(As1, 1, 1); stB(Bs1, 1, 1); stA(As1, 2, 1);
  VMW5();  // oldest 7 (= all of tile0) landed; tile1's 5 still in flight
  BARRIER();

#pragma unroll 1
  for (int t2 = 0; t2 < 16; t2 += 2) {
    KTILE(As0, Bs0, As1, Bs1, t2);
    KTILE(As1, Bs1, As0, Bs0, t2 + 1);
  }

  // epilogue: C row = bm*256 + 32*i + wr*16 + quad*4 + r ; col = bn*192 + wc*48 + 16*j + l15
#pragma unroll
  for (int i = 0; i < 8; i++) {
#pragma unroll
    for (int j = 0; j < 3; j++) {
      const int n = bn * 192 + wc * 48 + j * 16 + l15;
      const int proj = (n - l15) >> 10;  // wave-uniform (16-aligned boundaries)
      const int nn = n & 1023, h = nn >> 6, hd = nn & 63;
      const int m0 = bm * 256 + i * 32 + wr * 16 + quad * 4;
      const int b = m0 >> 11, s0 = m0 & (Ssz - 1);
      if (proj == 0) {
#pragma unroll
        for (int r = 0; r < 4; r++)
          Qh[((size_t)(b * Hn + h) * Ssz + s0 + r) * HDsz + hd] =
              f2bf(acc[i][j][r] * (0.125f * LOG2E));
      } else if (proj == 1) {
#pragma unroll
        for (int r = 0; r < 4; r++)
          Kh[((size_t)(b * Hn + h) * Ssz + s0 + r) * HDsz + hd] = f2bf(acc[i][j][r]);
      } else {
        ushort4 o;
        o.x = f2bf(acc[i][j][0]); o.y = f2bf(acc[i][j][1]);
        o.z = f2bf(acc[i][j][2]); o.w = f2bf(acc[i][j][3]);
        *reinterpret_cast<ushort4*>(
            &Vth[((size_t)(b * Hn + h) * HDsz + hd) * Ssz + s0]) = o;
      }
    }
  }
}

// ---------- flash attention: 128-row tiles, balanced t-perm, S^T + reg P ----------
__global__ __launch_bounds__(256, 4)
void flash_kernel(const unsigned short* __restrict__ Q,
                  const unsigned short* __restrict__ Kg,
                  const unsigned short* __restrict__ Vt,
                  unsigned short* __restrict__ AO) {
  __shared__ unsigned short Ks[64 * 64];
  __shared__ unsigned short Vs[64 * 64];

  const int tid = threadIdx.x;
  const int w = tid >> 6, lane = tid & 63;
  const int l15 = lane & 15, quad = lane >> 4;
  const int rr = lane >> 3;

  const int linear = blockIdx.y * 16 + blockIdx.x;
  const int bh = (linear & 7) * 8 + ((linear >> 3) & 7);
  const int g = linear >> 6, gk = g >> 2, ga = g & 3;
  const int t = (gk == 0) ? 15 - ga : (gk == 1) ? 8 + ga : (gk == 2) ? 7 - ga : ga;

  const unsigned short* Qb = Q + (size_t)bh * Ssz * HDsz;
  const unsigned short* Kb = Kg + (size_t)bh * Ssz * HDsz;
  const unsigned short* Vb = Vt + (size_t)bh * HDsz * Ssz;
  const int b = bh / Hn, h = bh % Hn;

  const int hl = (l15 & 7) ^ ((l15 >> 3) << 2);

  const int q0 = t * 128;
  const int rowStart = q0 + w * 32;

  bf16x8 qf[2][2];
#pragma unroll
  for (int tm = 0; tm < 2; tm++)
#pragma unroll
    for (int ks = 0; ks < 2; ks++)
      qf[tm][ks] = *reinterpret_cast<const bf16x8*>(
          &Qb[(size_t)(rowStart + tm * 16 + l15) * HDsz + ks * 32 + quad * 8]);

  f32x4 oacc[2][4];
  float lpart[2] = {0.f, 0.f};
#pragma unroll
  for (int tm = 0; tm < 2; tm++)
#pragma unroll
    for (int tn = 0; tn < 4; tn++) oacc[tm][tn] = (f32x4){0.f, 0.f, 0.f, 0.f};

  const int nkb = 2 * t + 2;
  for (int kb = 0; kb < nkb; kb++) {
    const int kv0 = kb * 64;
#pragma unroll
    for (int i = 0; i < 2; i++) {
      const int r8 = w * 16 + i * 8;
      const int sc = (((lane & 7) ^ rr ^ (i << 2))) * 8;
      async_cp16(&Kb[(size_t)(kv0 + r8 + rr) * HDsz + sc], &Ks[r8 * 64]);
      async_cp16(&Vb[(size_t)(r8 + rr) * Ssz + kv0 + sc], &Vs[r8 * 64]);
    }
    __syncthreads();

    const bool skip = (kv0 >= rowStart + 32);
    if (!skip) {
      f32x4 sc[4][2];
#pragma unroll
      for (int tn = 0; tn < 4; tn++)
#pragma unroll
        for (int tm = 0; tm < 2; tm++) sc[tn][tm] = (f32x4){0.f, 0.f, 0.f, 0.f};
#pragma unroll
      for (int ks = 0; ks < 2; ks++) {
#pragma unroll
        for (int tn = 0; tn < 4; tn++) {
          const int rk = tn * 16 + l15;
          bf16x8 kf = *reinterpret_cast<const bf16x8*>(
              &Ks[rk * 64 + (((ks * 4 + quad) ^ hl) * 8)]);
#pragma unroll
          for (int tm = 0; tm < 2; tm++)
            sc[tn][tm] = MFMA32(kf, qf[tm][ks], sc[tn][tm]);
        }
      }

      const bool needMask = (kv0 + 63 > rowStart);
      if (needMask) {
#pragma unroll
        for (int tn = 0; tn < 4; tn++)
#pragma unroll
          for (int tm = 0; tm < 2; tm++) {
            const int qrow = rowStart + tm * 16 + l15;
#pragma unroll
            for (int r = 0; r < 4; r++)
              if (kv0 + tn * 16 + quad * 4 + r > qrow) sc[tn][tm][r] = -1e30f;
          }
      }

      unsigned int pk[4][2][2];
#pragma unroll
      for (int tn = 0; tn < 4; tn++)
#pragma unroll
        for (int tm = 0; tm < 2; tm++) {
          union { float f; unsigned int u; } e0, e1, e2, e3;
          e0.f = __builtin_amdgcn_exp2f(sc[tn][tm][0]);
          e1.f = __builtin_amdgcn_exp2f(sc[tn][tm][1]);
          e2.f = __builtin_amdgcn_exp2f(sc[tn][tm][2]);
          e3.f = __builtin_amdgcn_exp2f(sc[tn][tm][3]);
          lpart[tm] += (e0.f + e1.f) + (e2.f + e3.f);
          pk[tn][tm][0] = __builtin_amdgcn_perm(e1.u, e0.u, 0x07060302u);
          pk[tn][tm][1] = __builtin_amdgcn_perm(e3.u, e2.u, 0x07060302u);
        }

#pragma unroll
      for (int tn = 0; tn < 4; tn++) {
        bf16x4 pa[2];
#pragma unroll
        for (int tm = 0; tm < 2; tm++) {
          union { unsigned int u[2]; bf16x4 v; } cv;
          cv.u[0] = pk[tn][tm][0]; cv.u[1] = pk[tn][tm][1];
          pa[tm] = cv.v;
        }
#pragma unroll
        for (int to = 0; to < 4; to++) {
          const int rv = to * 16 + l15;
          const int chunk = tn * 2 + (quad >> 1);
          bf16x4 vf = *reinterpret_cast<const bf16x4*>(
              (const char*)Vs + rv * 128 + ((chunk ^ hl) * 16) + (quad & 1) * 8);
#pragma unroll
          for (int tm = 0; tm < 2; tm++)
            oacc[tm][to] = MFMA16(pa[tm], vf, oacc[tm][to]);
        }
      }
    }
    __syncthreads();
  }

#pragma unroll
  for (int tm = 0; tm < 2; tm++) {
    float lf = lpart[tm];
    lf += __shfl_xor(lf, 16);
    lf += __shfl_xor(lf, 32);
    float linv[4];
#pragma unroll
    for (int r = 0; r < 4; r++) {
      union { float f; int i; } cv;
      cv.f = lf;
      cv.i = __builtin_amdgcn_ds_bpermute((quad * 4 + r) * 4, cv.i);
      linv[r] = 1.f / cv.f;
    }
#pragma unroll
    for (int r = 0; r < 4; r++) {
      const int s = rowStart + tm * 16 + quad * 4 + r;
      const size_t m = (size_t)b * Ssz + s;
#pragma unroll
      for (int tn = 0; tn < 4; tn++) {
        const int n = h * HDsz + tn * 16 + l15;
        AO[m * Dsz + n] = f2bf(oacc[tm][tn][r] * linv[r]);
      }
    }
  }
}

extern "C" void kernel_launch(void* const* d_in, const int* in_sizes, int n_in,
                              void* d_out, int out_size, void* d_ws, size_t ws_size,
                              hipStream_t stream) {
  const float* x  = (const float*)d_in[0];
  const float* Wq = (const float*)d_in[1];
  const float* Wk = (const float*)d_in[2];
  const float* Wv = (const float*)d_in[3];
  const float* Wo = (const float*)d_in[4];
  const float* bo = (const float*)d_in[5];
  float* out = (float*)d_out;

  unsigned short* xb  = (unsigned short*)d_ws;
  unsigned short* Wqt = xb + (size_t)Msz * Dsz;   // Wqt/Wkt/Wvt consecutive = concat [3072][1024]
  unsigned short* Wkt = Wqt + (size_t)Dsz * Dsz;
  unsigned short* Wvt = Wkt + (size_t)Dsz * Dsz;
  unsigned short* Wot = Wvt + (size_t)Dsz * Dsz;
  unsigned short* Qh  = Wot + (size_t)Dsz * Dsz;
  unsigned short* Kh  = Qh + (size_t)Msz * Dsz;
  unsigned short* Vth = Kh + (size_t)Msz * Dsz;
  unsigned short* AO  = Vth + (size_t)Msz * Dsz;

  prep_kernel<<<dim3(32, 32, 5), 256, 0, stream>>>(
      x, xb, Wq, Wk, Wv, Wo, Wqt, Wkt, Wvt, Wot);

  // fused QKV projection: 256x192 tiles, 8-phase counted-vmcnt, 512 blocks = 2 rounds
  gemm192_qkv<<<dim3(16, 32), 512, 0, stream>>>(xb, Wqt, Qh, Kh, Vth);

  flash_kernel<<<dim3(16, Bsz * Hn), 256, 0, stream>>>(Qh, Kh, Vth, AO);

  gemm_bk64<EPI_OUT><<<dim3(Dsz / 128, Msz / 128), 512, 0, stream>>>(
      AO, Wot, nullptr, nullptr, nullptr, out, bo);
}